// Round 3
// baseline (436.857 us; speedup 1.0000x reference)
//
#include <hip/hip_runtime.h>

#define NB 64      // L*B batches
#define T 1024     // t1 == t2
#define HD 128     // h

// encoded +inf for order-preserving float-as-uint atomicMin
#define EINF 0xFF800000u

typedef __attribute__((ext_vector_type(8))) short bf16x8;
typedef __attribute__((ext_vector_type(4))) float f32x4;

static __device__ __forceinline__ short f2bf(float f) {
    unsigned u = __float_as_uint(f);
    u += 0x7FFFu + ((u >> 16) & 1u);
    return (short)(u >> 16);
}
static __device__ __forceinline__ unsigned fenc(float f) {
    unsigned b = __float_as_uint(f);
    return b ^ (unsigned)(((int)b >> 31) | (int)0x80000000);
}
static __device__ __forceinline__ float fdec(unsigned u) {
    unsigned m = (~(unsigned)((int)u >> 31)) | 0x80000000u;
    return __uint_as_float(u ^ m);
}

// Phase 0: y fp32 -> bf16 + y row norms + workspace init. ~51 MB, pure BW.
__global__ void wmd_prep(const float* __restrict__ y, short* __restrict__ ybf,
                         float* __restrict__ y2,
                         unsigned* __restrict__ g_colmin, unsigned* __restrict__ g_rowmin,
                         float* __restrict__ sums, unsigned* __restrict__ batch_cnt,
                         unsigned* __restrict__ g_cnt) {
    int gi = blockIdx.x * 256 + threadIdx.x;          // float4 index, 2.097M total
    float4 vy = reinterpret_cast<const float4*>(y)[gi];
    short4 sy;
    sy.x = f2bf(vy.x); sy.y = f2bf(vy.y); sy.z = f2bf(vy.z); sy.w = f2bf(vy.w);
    reinterpret_cast<short4*>(ybf)[gi] = sy;
    float py = vy.x * vy.x + vy.y * vy.y + vy.z * vy.z + vy.w * vy.w;
    py += __shfl_xor(py, 1);  py += __shfl_xor(py, 2);  py += __shfl_xor(py, 4);
    py += __shfl_xor(py, 8);  py += __shfl_xor(py, 16);
    if ((threadIdx.x & 31) == 0) y2[gi >> 5] = py;
    if (gi < NB * T) { g_colmin[gi] = EINF; g_rowmin[gi] = EINF; }
    if (gi < 2) sums[gi] = 0.f;
    if (gi >= 4 && gi < 4 + NB) batch_cnt[gi - 4] = 0u;
    if (gi == 4 + NB) g_cnt[0] = 0u;
}

// Phase 1: fused bf16-MFMA GEMM + min tracking + fence-free per-batch reduce.
// Round-3 change (ONE variable vs round 2): occupancy. Rounds 0/2 both sat at
// ~45 us with MfmaUtil 14% / VALUBusy 28% / 4 blocks/CU — latency-bound, not
// pipeline-depth-bound (counted vmcnt was neutral). This round: 2048 blocks x
// 256 threads, per-block 128 rows x 256 cols, LDS cut to ~18.6 KB (2-slot
// 8 KB ring), __launch_bounds__(256, 8) -> 8 blocks/CU = 32 waves/CU (full).
// Inner loop verbatim round 2 (bv[2]/acc[2][2]/16 MFMA per 32-col phase, same
// XOR swizzle); sync is plain __syncthreads double-buffering — each block's
// drain is covered by the 7 other resident blocks (TLP, not ILP).
// bid&7 picks the XCD slot: all 32 blocks of a batch share one XCD's L2.
__global__ __launch_bounds__(256, 8)
void wmd_main(const float* __restrict__ x, const short* __restrict__ ybf,
              const float* __restrict__ y2g,
              unsigned* __restrict__ g_colmin, unsigned* __restrict__ g_rowmin,
              float* __restrict__ sums, unsigned* __restrict__ batch_cnt,
              unsigned* __restrict__ g_cnt, float* __restrict__ out) {
    __shared__ short b_sm[2][32 * 128];        // 2 x 8 KB ring
    __shared__ float y2_sm[256];
    __shared__ float x2_sm[128];
    __shared__ unsigned col_min_sm[256];
    __shared__ unsigned last_sm;
    __shared__ float red_sm[8];

    const int tid  = threadIdx.x;
    const int bid  = blockIdx.x;                           // 0..2047
    const int n    = ((bid & 7) << 3) | ((bid >> 3) & 7);  // batch; xcd = n>>3
    const int tle  = bid >> 6;                             // 0..31
    const int m    = tle >> 2;                             // i-tile (128 rows)
    const int jq   = tle & 3;                              // j-quarter (256 cols)
    const int i0   = m * 128;
    const int j0   = jq * 256;
    const int lane = tid & 63;
    const int wave = tid >> 6;
    const int l16  = lane & 15, quad = lane >> 4;
    const float FINF = __uint_as_float(0x7F800000u);

    if (tid < 256) col_min_sm[tid] = EINF;

// per wave: 2 x global_load_lds(16B) per 32-col tile; linear LDS dest,
// XOR-swizzled global source (reader applies the same XOR).
#define ISSUE_GLLS(pbuf, jtile)                                                   \
    {                                                                             \
        const short* ybase = ybf + (((size_t)(n * T + j0 + (jtile) * 32)) << 7);  \
        _Pragma("unroll")                                                         \
        for (int it = 0; it < 2; ++it) {                                          \
            int g   = wave * 2 + it;                                              \
            int s   = g * 64 + lane;                                              \
            int row = s >> 4;                                                     \
            int c   = (s & 15) ^ (row & 7);                                       \
            const short* gp = ybase + row * 128 + c * 8;                          \
            __builtin_amdgcn_global_load_lds(                                     \
                (const __attribute__((address_space(1))) void*)gp,                \
                (__attribute__((address_space(3))) void*)&b_sm[pbuf][g * 512],    \
                16, 0, 0);                                                        \
        }                                                                         \
    }

    ISSUE_GLLS(0, 0);   // tile-0 DMA overlaps the prologue

    // ---- A fragments: fp32 x -> bf16 regs + exact fp32 row norms ----
    bf16x8 af[2][4];
    #pragma unroll
    for (int mi = 0; mi < 2; ++mi) {
        float part = 0.f;
        #pragma unroll
        for (int kk = 0; kk < 4; ++kk) {
            const float4* gp = reinterpret_cast<const float4*>(
                x + (((size_t)(n * T + i0 + wave * 32 + mi * 16 + l16)) << 7) + kk * 32 + quad * 8);
            float4 a = gp[0], b = gp[1];
            bf16x8 f;
            f[0] = f2bf(a.x); f[1] = f2bf(a.y); f[2] = f2bf(a.z); f[3] = f2bf(a.w);
            f[4] = f2bf(b.x); f[5] = f2bf(b.y); f[6] = f2bf(b.z); f[7] = f2bf(b.w);
            af[mi][kk] = f;
            part += a.x * a.x + a.y * a.y + a.z * a.z + a.w * a.w;
            part += b.x * b.x + b.y * b.y + b.z * b.z + b.w * b.w;
        }
        part += __shfl_xor(part, 16);
        part += __shfl_xor(part, 32);
        if (quad == 0) x2_sm[wave * 32 + mi * 16 + l16] = part;
    }
    if (tid < 256) y2_sm[tid] = y2g[n * T + j0 + tid];

    float rmin[8];
    #pragma unroll
    for (int q = 0; q < 8; ++q) rmin[q] = FINF;

    __syncthreads();    // x2_sm/y2_sm visible; tile-0 DMA drained

    float x2v[8];
    #pragma unroll
    for (int mi = 0; mi < 2; ++mi)
        #pragma unroll
        for (int r = 0; r < 4; ++r)
            x2v[mi * 4 + r] = x2_sm[wave * 32 + mi * 16 + quad * 4 + r];

    for (int jt = 0; jt < 8; ++jt) {
        const int p = jt & 1;
        if (jt < 7) ISSUE_GLLS(p ^ 1, jt + 1);   // overlaps this iter's compute

        float y2v[2];
        #pragma unroll
        for (int ni = 0; ni < 2; ++ni)
            y2v[ni] = y2_sm[jt * 32 + ni * 16 + l16];

        f32x4 acc[2][2];
        #pragma unroll
        for (int mi = 0; mi < 2; ++mi)
            #pragma unroll
            for (int ni = 0; ni < 2; ++ni) {
                f32x4 z = {0.f, 0.f, 0.f, 0.f};
                acc[mi][ni] = z;
            }

        #pragma unroll
        for (int kk = 0; kk < 4; ++kk) {
            bf16x8 bv[2];
            #pragma unroll
            for (int ni = 0; ni < 2; ++ni) {
                int row = ni * 16 + l16;
                int c   = (kk * 4 + quad) ^ (row & 7);
                bv[ni] = *reinterpret_cast<const bf16x8*>(&b_sm[p][(row * 16 + c) * 8]);
            }
            #pragma unroll
            for (int mi = 0; mi < 2; ++mi)
                #pragma unroll
                for (int ni = 0; ni < 2; ++ni)
                    acc[mi][ni] = __builtin_amdgcn_mfma_f32_16x16x32_bf16(
                        af[mi][kk], bv[ni], acc[mi][ni], 0, 0, 0);
        }

        // ---- epilogue: fold mins (norm-add deferred to flush) ----
        float vcol[2] = {FINF, FINF};
        #pragma unroll
        for (int mi = 0; mi < 2; ++mi)
            #pragma unroll
            for (int r = 0; r < 4; ++r) {
                float x2r = x2v[mi * 4 + r];
                #pragma unroll
                for (int ni = 0; ni < 2; ++ni) {
                    float xy = acc[mi][ni][r];
                    rmin[mi * 4 + r] = fminf(rmin[mi * 4 + r], fmaf(-2.f, xy, y2v[ni]));
                    vcol[ni]         = fminf(vcol[ni],         fmaf(-2.f, xy, x2r));
                }
            }
        #pragma unroll
        for (int ni = 0; ni < 2; ++ni) {
            float v = vcol[ni];
            v = fminf(v, __shfl_xor(v, 16));
            v = fminf(v, __shfl_xor(v, 32));
            if (lane < 16)
                atomicMin(&col_min_sm[jt * 32 + ni * 16 + lane], fenc(v));
        }
        __syncthreads();   // drains next-tile DMA; orders buffer reuse
    }

    // ---- flush mins to global with norms pre-added (device-scope atomics) ----
    if (tid < 256) {
        float v = fdec(col_min_sm[tid]) + y2_sm[tid];       // + y2_j for col tid
        atomicMin(&g_colmin[n * T + j0 + tid], fenc(v));
    }
    #pragma unroll
    for (int mi = 0; mi < 2; ++mi)
        #pragma unroll
        for (int r = 0; r < 4; ++r) {
            float v = rmin[mi * 4 + r] + x2v[mi * 4 + r];   // + x2_i for this row
            v = fminf(v, __shfl_xor(v, 1));
            v = fminf(v, __shfl_xor(v, 2));
            v = fminf(v, __shfl_xor(v, 4));
            v = fminf(v, __shfl_xor(v, 8));
            if (l16 == 0)
                atomicMin(&g_rowmin[n * T + i0 + wave * 32 + mi * 16 + quad * 4 + r], fenc(v));
        }

    // ---- fence-free completion protocol (32 blocks per batch) ----
    __builtin_amdgcn_s_waitcnt(0);   // this wave's atomics acked at coherent point
    __syncthreads();                 // all waves of block done
    if (tid == 0)
        last_sm = __hip_atomic_fetch_add(&batch_cnt[n], 1u, __ATOMIC_RELAXED,
                                         __HIP_MEMORY_SCOPE_AGENT);
    __syncthreads();
    if (last_sm != 31u) return;

    // last block of batch n: reduce its 1024 row/col mins (already full d^2)
    float sc = 0.f, sr = 0.f;
    for (int e = tid; e < T; e += 256) {
        unsigned cu = __hip_atomic_load(&g_colmin[n * T + e], __ATOMIC_RELAXED,
                                        __HIP_MEMORY_SCOPE_AGENT);
        unsigned ru = __hip_atomic_load(&g_rowmin[n * T + e], __ATOMIC_RELAXED,
                                        __HIP_MEMORY_SCOPE_AGENT);
        sc += sqrtf(fmaxf(fdec(cu), 0.f));
        sr += sqrtf(fmaxf(fdec(ru), 0.f));
    }
    #pragma unroll
    for (int o = 1; o < 64; o <<= 1) {
        sc += __shfl_xor(sc, o);
        sr += __shfl_xor(sr, o);
    }
    if (lane == 0) { red_sm[wave] = sc; red_sm[4 + wave] = sr; }
    __syncthreads();
    if (tid == 0) {
        atomicAdd(&sums[0], red_sm[0] + red_sm[1] + red_sm[2] + red_sm[3]);
        atomicAdd(&sums[1], red_sm[4] + red_sm[5] + red_sm[6] + red_sm[7]);
        __builtin_amdgcn_s_waitcnt(0);   // sums adds acked before counter bump
        unsigned old = __hip_atomic_fetch_add(g_cnt, 1u, __ATOMIC_RELAXED,
                                              __HIP_MEMORY_SCOPE_AGENT);
        if (old == NB - 1) {
            float a = __hip_atomic_load(&sums[0], __ATOMIC_RELAXED, __HIP_MEMORY_SCOPE_AGENT);
            float b = __hip_atomic_load(&sums[1], __ATOMIC_RELAXED, __HIP_MEMORY_SCOPE_AGENT);
            out[0] = fmaxf(a, b) * (1.0f / 67108864.0f);
        }
    }
}

extern "C" void kernel_launch(void* const* d_in, const int* in_sizes, int n_in,
                              void* d_out, int out_size, void* d_ws, size_t ws_size,
                              hipStream_t stream) {
    const float* x = (const float*)d_in[0];
    const float* y = (const float*)d_in[1];
    float* out = (float*)d_out;

    char* ws = (char*)d_ws;
    unsigned* g_colmin  = (unsigned*)(ws);                     // 256 KB
    unsigned* g_rowmin  = (unsigned*)(ws + 256 * 1024);        // 256 KB
    float*    y2g       = (float*)(ws + 512 * 1024);           // 256 KB
    float*    sums      = (float*)(ws + 768 * 1024);           // 2 f32
    unsigned* batch_cnt = (unsigned*)(ws + 768 * 1024 + 256);  // 64 u32
    unsigned* g_cnt     = (unsigned*)(ws + 768 * 1024 + 2048); // 1 u32
    short*    ybf       = (short*)(ws + 1024 * 1024);          // 16 MB

    wmd_prep<<<(NB * T * HD / 4) / 256, 256, 0, stream>>>(
        y, ybf, y2g, g_colmin, g_rowmin, sums, batch_cnt, g_cnt);
    wmd_main<<<dim3(2048), 256, 0, stream>>>(
        x, ybf, y2g, g_colmin, g_rowmin, sums, batch_cnt, g_cnt, out);
}

// Round 4
// 220.204 us; speedup vs baseline: 1.9839x; 1.9839x over previous
//
#include <hip/hip_runtime.h>

#define NB 64      // L*B batches
#define T 1024     // t1 == t2
#define HD 128     // h

// encoded +inf for order-preserving float-as-uint atomicMin
#define EINF 0xFF800000u

typedef __attribute__((ext_vector_type(8))) short bf16x8;
typedef __attribute__((ext_vector_type(4))) float f32x4;

static __device__ __forceinline__ short f2bf(float f) {
    unsigned u = __float_as_uint(f);
    u += 0x7FFFu + ((u >> 16) & 1u);
    return (short)(u >> 16);
}
static __device__ __forceinline__ unsigned fenc(float f) {
    unsigned b = __float_as_uint(f);
    return b ^ (unsigned)(((int)b >> 31) | (int)0x80000000);
}
static __device__ __forceinline__ float fdec(unsigned u) {
    unsigned m = (~(unsigned)((int)u >> 31)) | 0x80000000u;
    return __uint_as_float(u ^ m);
}

// Phase 0: y fp32 -> bf16 + y row norms + workspace init. ~51 MB, pure BW.
__global__ void wmd_prep(const float* __restrict__ y, short* __restrict__ ybf,
                         float* __restrict__ y2,
                         unsigned* __restrict__ g_colmin, unsigned* __restrict__ g_rowmin,
                         float* __restrict__ sums, unsigned* __restrict__ batch_cnt,
                         unsigned* __restrict__ g_cnt) {
    int gi = blockIdx.x * 256 + threadIdx.x;          // float4 index, 2.097M total
    float4 vy = reinterpret_cast<const float4*>(y)[gi];
    short4 sy;
    sy.x = f2bf(vy.x); sy.y = f2bf(vy.y); sy.z = f2bf(vy.z); sy.w = f2bf(vy.w);
    reinterpret_cast<short4*>(ybf)[gi] = sy;
    float py = vy.x * vy.x + vy.y * vy.y + vy.z * vy.z + vy.w * vy.w;
    py += __shfl_xor(py, 1);  py += __shfl_xor(py, 2);  py += __shfl_xor(py, 4);
    py += __shfl_xor(py, 8);  py += __shfl_xor(py, 16);
    if ((threadIdx.x & 31) == 0) y2[gi >> 5] = py;
    if (gi < NB * T) { g_colmin[gi] = EINF; g_rowmin[gi] = EINF; }
    if (gi < 2) sums[gi] = 0.f;
    if (gi >= 4 && gi < 4 + NB) batch_cnt[gi - 4] = 0u;
    if (gi == 4 + NB) g_cnt[0] = 0u;
}

// Phase 1: fused bf16-MFMA GEMM + min tracking + fence-free per-batch reduce.
// Round-4 change (ONE variable vs round 3): __launch_bounds__ back to (256,4).
// Round-3 post-mortem: (256,8) capped the allocator at 64 regs/thread -> VGPR 32
// + massive scratch spill (WRITE 4->438 MB, 1.2 GB total traffic, 356 us) even
// though occupancy hit 75% — occupancy at any register price is a loss. Rounds
// 0/2 prove the natural allocation is ~60-64 VGPR at (256,4), which ALREADY
// fits 8 waves/SIMD (64x8=512); the old 4-block/CU limit was LDS (37.9 KB).
// This round keeps round-3's 19.4 KB-LDS / 2048-block / 128x256-tile shape so
// LDS allows 8 blocks/CU, and lets the allocator keep its proven 60-64-reg
// codegen. Expected: zero spill + 6-8 blocks/CU = 24-32 waves (vs 16).
// bid&7 picks the XCD slot: all 32 blocks of a batch share one XCD's L2.
__global__ __launch_bounds__(256, 4)
void wmd_main(const float* __restrict__ x, const short* __restrict__ ybf,
              const float* __restrict__ y2g,
              unsigned* __restrict__ g_colmin, unsigned* __restrict__ g_rowmin,
              float* __restrict__ sums, unsigned* __restrict__ batch_cnt,
              unsigned* __restrict__ g_cnt, float* __restrict__ out) {
    __shared__ short b_sm[2][32 * 128];        // 2 x 8 KB ring
    __shared__ float y2_sm[256];
    __shared__ float x2_sm[128];
    __shared__ unsigned col_min_sm[256];
    __shared__ unsigned last_sm;
    __shared__ float red_sm[8];

    const int tid  = threadIdx.x;
    const int bid  = blockIdx.x;                           // 0..2047
    const int n    = ((bid & 7) << 3) | ((bid >> 3) & 7);  // batch; xcd = n>>3
    const int tle  = bid >> 6;                             // 0..31
    const int m    = tle >> 2;                             // i-tile (128 rows)
    const int jq   = tle & 3;                              // j-quarter (256 cols)
    const int i0   = m * 128;
    const int j0   = jq * 256;
    const int lane = tid & 63;
    const int wave = tid >> 6;
    const int l16  = lane & 15, quad = lane >> 4;
    const float FINF = __uint_as_float(0x7F800000u);

    if (tid < 256) col_min_sm[tid] = EINF;

// per wave: 2 x global_load_lds(16B) per 32-col tile; linear LDS dest,
// XOR-swizzled global source (reader applies the same XOR).
#define ISSUE_GLLS(pbuf, jtile)                                                   \
    {                                                                             \
        const short* ybase = ybf + (((size_t)(n * T + j0 + (jtile) * 32)) << 7);  \
        _Pragma("unroll")                                                         \
        for (int it = 0; it < 2; ++it) {                                          \
            int g   = wave * 2 + it;                                              \
            int s   = g * 64 + lane;                                              \
            int row = s >> 4;                                                     \
            int c   = (s & 15) ^ (row & 7);                                       \
            const short* gp = ybase + row * 128 + c * 8;                          \
            __builtin_amdgcn_global_load_lds(                                     \
                (const __attribute__((address_space(1))) void*)gp,                \
                (__attribute__((address_space(3))) void*)&b_sm[pbuf][g * 512],    \
                16, 0, 0);                                                        \
        }                                                                         \
    }

    ISSUE_GLLS(0, 0);   // tile-0 DMA overlaps the prologue

    // ---- A fragments: fp32 x -> bf16 regs + exact fp32 row norms ----
    bf16x8 af[2][4];
    #pragma unroll
    for (int mi = 0; mi < 2; ++mi) {
        float part = 0.f;
        #pragma unroll
        for (int kk = 0; kk < 4; ++kk) {
            const float4* gp = reinterpret_cast<const float4*>(
                x + (((size_t)(n * T + i0 + wave * 32 + mi * 16 + l16)) << 7) + kk * 32 + quad * 8);
            float4 a = gp[0], b = gp[1];
            bf16x8 f;
            f[0] = f2bf(a.x); f[1] = f2bf(a.y); f[2] = f2bf(a.z); f[3] = f2bf(a.w);
            f[4] = f2bf(b.x); f[5] = f2bf(b.y); f[6] = f2bf(b.z); f[7] = f2bf(b.w);
            af[mi][kk] = f;
            part += a.x * a.x + a.y * a.y + a.z * a.z + a.w * a.w;
            part += b.x * b.x + b.y * b.y + b.z * b.z + b.w * b.w;
        }
        part += __shfl_xor(part, 16);
        part += __shfl_xor(part, 32);
        if (quad == 0) x2_sm[wave * 32 + mi * 16 + l16] = part;
    }
    if (tid < 256) y2_sm[tid] = y2g[n * T + j0 + tid];

    float rmin[8];
    #pragma unroll
    for (int q = 0; q < 8; ++q) rmin[q] = FINF;

    __syncthreads();    // x2_sm/y2_sm visible; tile-0 DMA drained

    float x2v[8];
    #pragma unroll
    for (int mi = 0; mi < 2; ++mi)
        #pragma unroll
        for (int r = 0; r < 4; ++r)
            x2v[mi * 4 + r] = x2_sm[wave * 32 + mi * 16 + quad * 4 + r];

    for (int jt = 0; jt < 8; ++jt) {
        const int p = jt & 1;
        if (jt < 7) ISSUE_GLLS(p ^ 1, jt + 1);   // overlaps this iter's compute

        float y2v[2];
        #pragma unroll
        for (int ni = 0; ni < 2; ++ni)
            y2v[ni] = y2_sm[jt * 32 + ni * 16 + l16];

        f32x4 acc[2][2];
        #pragma unroll
        for (int mi = 0; mi < 2; ++mi)
            #pragma unroll
            for (int ni = 0; ni < 2; ++ni) {
                f32x4 z = {0.f, 0.f, 0.f, 0.f};
                acc[mi][ni] = z;
            }

        #pragma unroll
        for (int kk = 0; kk < 4; ++kk) {
            bf16x8 bv[2];
            #pragma unroll
            for (int ni = 0; ni < 2; ++ni) {
                int row = ni * 16 + l16;
                int c   = (kk * 4 + quad) ^ (row & 7);
                bv[ni] = *reinterpret_cast<const bf16x8*>(&b_sm[p][(row * 16 + c) * 8]);
            }
            #pragma unroll
            for (int mi = 0; mi < 2; ++mi)
                #pragma unroll
                for (int ni = 0; ni < 2; ++ni)
                    acc[mi][ni] = __builtin_amdgcn_mfma_f32_16x16x32_bf16(
                        af[mi][kk], bv[ni], acc[mi][ni], 0, 0, 0);
        }

        // ---- epilogue: fold mins (norm-add deferred to flush) ----
        float vcol[2] = {FINF, FINF};
        #pragma unroll
        for (int mi = 0; mi < 2; ++mi)
            #pragma unroll
            for (int r = 0; r < 4; ++r) {
                float x2r = x2v[mi * 4 + r];
                #pragma unroll
                for (int ni = 0; ni < 2; ++ni) {
                    float xy = acc[mi][ni][r];
                    rmin[mi * 4 + r] = fminf(rmin[mi * 4 + r], fmaf(-2.f, xy, y2v[ni]));
                    vcol[ni]         = fminf(vcol[ni],         fmaf(-2.f, xy, x2r));
                }
            }
        #pragma unroll
        for (int ni = 0; ni < 2; ++ni) {
            float v = vcol[ni];
            v = fminf(v, __shfl_xor(v, 16));
            v = fminf(v, __shfl_xor(v, 32));
            if (lane < 16)
                atomicMin(&col_min_sm[jt * 32 + ni * 16 + lane], fenc(v));
        }
        __syncthreads();   // drains next-tile DMA; orders buffer reuse
    }

    // ---- flush mins to global with norms pre-added (device-scope atomics) ----
    if (tid < 256) {
        float v = fdec(col_min_sm[tid]) + y2_sm[tid];       // + y2_j for col tid
        atomicMin(&g_colmin[n * T + j0 + tid], fenc(v));
    }
    #pragma unroll
    for (int mi = 0; mi < 2; ++mi)
        #pragma unroll
        for (int r = 0; r < 4; ++r) {
            float v = rmin[mi * 4 + r] + x2v[mi * 4 + r];   // + x2_i for this row
            v = fminf(v, __shfl_xor(v, 1));
            v = fminf(v, __shfl_xor(v, 2));
            v = fminf(v, __shfl_xor(v, 4));
            v = fminf(v, __shfl_xor(v, 8));
            if (l16 == 0)
                atomicMin(&g_rowmin[n * T + i0 + wave * 32 + mi * 16 + quad * 4 + r], fenc(v));
        }

    // ---- fence-free completion protocol (32 blocks per batch) ----
    __builtin_amdgcn_s_waitcnt(0);   // this wave's atomics acked at coherent point
    __syncthreads();                 // all waves of block done
    if (tid == 0)
        last_sm = __hip_atomic_fetch_add(&batch_cnt[n], 1u, __ATOMIC_RELAXED,
                                         __HIP_MEMORY_SCOPE_AGENT);
    __syncthreads();
    if (last_sm != 31u) return;

    // last block of batch n: reduce its 1024 row/col mins (already full d^2)
    float sc = 0.f, sr = 0.f;
    for (int e = tid; e < T; e += 256) {
        unsigned cu = __hip_atomic_load(&g_colmin[n * T + e], __ATOMIC_RELAXED,
                                        __HIP_MEMORY_SCOPE_AGENT);
        unsigned ru = __hip_atomic_load(&g_rowmin[n * T + e], __ATOMIC_RELAXED,
                                        __HIP_MEMORY_SCOPE_AGENT);
        sc += sqrtf(fmaxf(fdec(cu), 0.f));
        sr += sqrtf(fmaxf(fdec(ru), 0.f));
    }
    #pragma unroll
    for (int o = 1; o < 64; o <<= 1) {
        sc += __shfl_xor(sc, o);
        sr += __shfl_xor(sr, o);
    }
    if (lane == 0) { red_sm[wave] = sc; red_sm[4 + wave] = sr; }
    __syncthreads();
    if (tid == 0) {
        atomicAdd(&sums[0], red_sm[0] + red_sm[1] + red_sm[2] + red_sm[3]);
        atomicAdd(&sums[1], red_sm[4] + red_sm[5] + red_sm[6] + red_sm[7]);
        __builtin_amdgcn_s_waitcnt(0);   // sums adds acked before counter bump
        unsigned old = __hip_atomic_fetch_add(g_cnt, 1u, __ATOMIC_RELAXED,
                                              __HIP_MEMORY_SCOPE_AGENT);
        if (old == NB - 1) {
            float a = __hip_atomic_load(&sums[0], __ATOMIC_RELAXED, __HIP_MEMORY_SCOPE_AGENT);
            float b = __hip_atomic_load(&sums[1], __ATOMIC_RELAXED, __HIP_MEMORY_SCOPE_AGENT);
            out[0] = fmaxf(a, b) * (1.0f / 67108864.0f);
        }
    }
}

extern "C" void kernel_launch(void* const* d_in, const int* in_sizes, int n_in,
                              void* d_out, int out_size, void* d_ws, size_t ws_size,
                              hipStream_t stream) {
    const float* x = (const float*)d_in[0];
    const float* y = (const float*)d_in[1];
    float* out = (float*)d_out;

    char* ws = (char*)d_ws;
    unsigned* g_colmin  = (unsigned*)(ws);                     // 256 KB
    unsigned* g_rowmin  = (unsigned*)(ws + 256 * 1024);        // 256 KB
    float*    y2g       = (float*)(ws + 512 * 1024);           // 256 KB
    float*    sums      = (float*)(ws + 768 * 1024);           // 2 f32
    unsigned* batch_cnt = (unsigned*)(ws + 768 * 1024 + 256);  // 64 u32
    unsigned* g_cnt     = (unsigned*)(ws + 768 * 1024 + 2048); // 1 u32
    short*    ybf       = (short*)(ws + 1024 * 1024);          // 16 MB

    wmd_prep<<<(NB * T * HD / 4) / 256, 256, 0, stream>>>(
        y, ybf, y2g, g_colmin, g_rowmin, sums, batch_cnt, g_cnt);
    wmd_main<<<dim3(2048), 256, 0, stream>>>(
        x, ybf, y2g, g_colmin, g_rowmin, sums, batch_cnt, g_cnt, out);
}

// Round 5
// 160.795 us; speedup vs baseline: 2.7169x; 1.3695x over previous
//
#include <hip/hip_runtime.h>

#define NB 64      // L*B batches
#define T 1024     // t1 == t2
#define HD 128     // h

// encoded +inf for order-preserving float-as-uint atomicMin
#define EINF 0xFF800000u

typedef __attribute__((ext_vector_type(8))) short bf16x8;
typedef __attribute__((ext_vector_type(4))) float f32x4;

static __device__ __forceinline__ short f2bf(float f) {
    unsigned u = __float_as_uint(f);
    u += 0x7FFFu + ((u >> 16) & 1u);
    return (short)(u >> 16);
}
static __device__ __forceinline__ unsigned fenc(float f) {
    unsigned b = __float_as_uint(f);
    return b ^ (unsigned)(((int)b >> 31) | (int)0x80000000);
}
static __device__ __forceinline__ float fdec(unsigned u) {
    unsigned m = (~(unsigned)((int)u >> 31)) | 0x80000000u;
    return __uint_as_float(u ^ m);
}

// Phase 0: y fp32 -> bf16 + y row norms + workspace init. ~51 MB, pure BW.
__global__ void wmd_prep(const float* __restrict__ y, short* __restrict__ ybf,
                         float* __restrict__ y2,
                         unsigned* __restrict__ g_colmin, unsigned* __restrict__ g_rowmin,
                         float* __restrict__ sums, unsigned* __restrict__ batch_cnt,
                         unsigned* __restrict__ g_cnt) {
    int gi = blockIdx.x * 256 + threadIdx.x;          // float4 index, 2.097M total
    float4 vy = reinterpret_cast<const float4*>(y)[gi];
    short4 sy;
    sy.x = f2bf(vy.x); sy.y = f2bf(vy.y); sy.z = f2bf(vy.z); sy.w = f2bf(vy.w);
    reinterpret_cast<short4*>(ybf)[gi] = sy;
    float py = vy.x * vy.x + vy.y * vy.y + vy.z * vy.z + vy.w * vy.w;
    py += __shfl_xor(py, 1);  py += __shfl_xor(py, 2);  py += __shfl_xor(py, 4);
    py += __shfl_xor(py, 8);  py += __shfl_xor(py, 16);
    if ((threadIdx.x & 31) == 0) y2[gi >> 5] = py;
    if (gi < NB * T) { g_colmin[gi] = EINF; g_rowmin[gi] = EINF; }
    if (gi < 2) sums[gi] = 0.f;
    if (gi >= 4 && gi < 4 + NB) batch_cnt[gi - 4] = 0u;
    if (gi == 4 + NB) g_cnt[0] = 0u;
}

// Phase 1: fused bf16-MFMA GEMM + min tracking + fence-free per-batch reduce.
// Round-5 redesign: NO LDS STAGING OF B, NO MAIN-LOOP BARRIERS.
// Rationale (rounds 0-4 post-mortems): the round-0 structure's 44 us is NOT
// DMA-drain (counted vmcnt neutral, r2) and NOT wave-count (r3/r4 spilled or
// thrashed); its per-CU pipe sums (~LDS 15 us + VALU 10 + MFMA 7) say the
// loss is the 8x per-phase lockstep {staging-barrier + 4x wave-amplified LDS
// reads}. A batch's ybf panel is 256 KB — it L2-FITS (4 MB/XCD): staging it
// through LDS is pure overhead (Common-mistake #7).
// Structure: grid dim3(16, NB) (the proven clean envelope: 2-D, 1024 blocks,
// no swizzle). Block = 64 rows x 1024 cols (full j): x read exactly once;
// 16 blocks/batch -> round-0 completion protocol unchanged. 4 waves split
// along j: wave w owns cols w*256 as 16 chunks of 16; each wave holds all
// 64 A-rows in regs (af[4][4], 64 VGPR -> 2x rows/wave = half the B-read
// amplification of round 0). B fragments are plain global loads from ybf
// (L2-hot, 16 B/lane); col-min via LDS atomics (order-free, no barrier);
// row-min cross-wave combine once at the end. Main loop has ZERO barriers.
// __launch_bounds__(256,3): peak live regs ~135 < 170 cap (the (256,4) 128
// cap would spill — rounds 1/3/4 lesson: never cap below natural allocation).
__global__ __launch_bounds__(256, 3)
void wmd_main(const float* __restrict__ x, const short* __restrict__ ybf,
              const float* __restrict__ y2g,
              unsigned* __restrict__ g_colmin, unsigned* __restrict__ g_rowmin,
              float* __restrict__ sums, unsigned* __restrict__ batch_cnt,
              unsigned* __restrict__ g_cnt, float* __restrict__ out) {
    __shared__ float y2_sm[1024];
    __shared__ float x2_sm[64];
    __shared__ unsigned col_min_sm[1024];
    __shared__ unsigned row_min_sm[64];
    __shared__ unsigned last_sm;
    __shared__ float red_sm[8];

    const int tid  = threadIdx.x;
    const int m    = blockIdx.x;          // i-tile 0..15 (64 rows)
    const int n    = blockIdx.y;          // batch 0..63
    const int i0   = m * 64;
    const int lane = tid & 63;
    const int wave = tid >> 6;            // 0..3: j-stripe owner (cols wave*256)
    const int l16  = lane & 15, quad = lane >> 4;
    const float FINF = __uint_as_float(0x7F800000u);

    #pragma unroll
    for (int e = tid; e < 1024; e += 256) col_min_sm[e] = EINF;
    if (tid < 64) row_min_sm[tid] = EINF;

    // ---- A fragments: fp32 x -> bf16 regs + exact fp32 row norms ----
    // All 4 waves load the same 64-row panel (32 KB, L1/L2-resident after
    // wave 0's touch); wave 0 publishes the norms.
    bf16x8 af[4][4];
    #pragma unroll
    for (int mi = 0; mi < 4; ++mi) {
        float part = 0.f;
        #pragma unroll
        for (int kk = 0; kk < 4; ++kk) {
            const float4* gp = reinterpret_cast<const float4*>(
                x + (((size_t)(n * T + i0 + mi * 16 + l16)) << 7) + kk * 32 + quad * 8);
            float4 a = gp[0], b = gp[1];
            bf16x8 f;
            f[0] = f2bf(a.x); f[1] = f2bf(a.y); f[2] = f2bf(a.z); f[3] = f2bf(a.w);
            f[4] = f2bf(b.x); f[5] = f2bf(b.y); f[6] = f2bf(b.z); f[7] = f2bf(b.w);
            af[mi][kk] = f;
            part += a.x * a.x + a.y * a.y + a.z * a.z + a.w * a.w;
            part += b.x * b.x + b.y * b.y + b.z * b.z + b.w * b.w;
        }
        part += __shfl_xor(part, 16);
        part += __shfl_xor(part, 32);
        if (wave == 0 && quad == 0) x2_sm[mi * 16 + l16] = part;
    }
    #pragma unroll
    for (int e = tid; e < 1024; e += 256) y2_sm[e] = y2g[n * T + e];

    float rmin[16];
    #pragma unroll
    for (int q = 0; q < 16; ++q) rmin[q] = FINF;

    __syncthreads();    // x2_sm / y2_sm / min-array init visible

    float x2v[16];
    #pragma unroll
    for (int mi = 0; mi < 4; ++mi)
        #pragma unroll
        for (int r = 0; r < 4; ++r)
            x2v[mi * 4 + r] = x2_sm[mi * 16 + quad * 4 + r];

    // ---- main loop: 16 chunks of 16 cols; barrier-free ----
    const short* ybase = ybf + (((size_t)(n * T + wave * 256 + l16)) << 7) + quad * 8;
    #pragma unroll 2
    for (int c = 0; c < 16; ++c) {
        const int jcol = wave * 256 + c * 16 + l16;   // this lane's column
        float y2v = y2_sm[jcol];

        f32x4 acc[4];
        #pragma unroll
        for (int mi = 0; mi < 4; ++mi) {
            f32x4 z = {0.f, 0.f, 0.f, 0.f};
            acc[mi] = z;
        }

        #pragma unroll
        for (int kk = 0; kk < 4; ++kk) {
            // B fragment straight from L2: row j = jcol, k-slot = kk*32+quad*8
            bf16x8 bv = *reinterpret_cast<const bf16x8*>(
                ybase + ((size_t)(c * 16) << 7) + kk * 32);
            #pragma unroll
            for (int mi = 0; mi < 4; ++mi)
                acc[mi] = __builtin_amdgcn_mfma_f32_16x16x32_bf16(
                    af[mi][kk], bv, acc[mi], 0, 0, 0);
        }

        // ---- epilogue: fold mins (norm-add deferred) ----
        float vcol = FINF;
        #pragma unroll
        for (int mi = 0; mi < 4; ++mi)
            #pragma unroll
            for (int r = 0; r < 4; ++r) {
                float xy = acc[mi][r];
                rmin[mi * 4 + r] = fminf(rmin[mi * 4 + r], fmaf(-2.f, xy, y2v));
                vcol             = fminf(vcol,             fmaf(-2.f, xy, x2v[mi * 4 + r]));
            }
        vcol = fminf(vcol, __shfl_xor(vcol, 16));
        vcol = fminf(vcol, __shfl_xor(vcol, 32));
        if (lane < 16)
            atomicMin(&col_min_sm[wave * 256 + c * 16 + lane], fenc(vcol));
    }

    // ---- row-min: fold over l16, combine across waves via LDS atomics ----
    #pragma unroll
    for (int e = 0; e < 16; ++e) {
        float v = rmin[e];
        v = fminf(v, __shfl_xor(v, 1));
        v = fminf(v, __shfl_xor(v, 2));
        v = fminf(v, __shfl_xor(v, 4));
        v = fminf(v, __shfl_xor(v, 8));
        if (l16 == 0) {
            int row = (e >> 2) * 16 + quad * 4 + (e & 3);   // mi*16 + quad*4 + r
            atomicMin(&row_min_sm[row], fenc(v + x2v[e]));  // + x2_i here
        }
    }
    __syncthreads();   // col_min_sm / row_min_sm complete

    // ---- flush to global (device-scope atomics, norms included) ----
    #pragma unroll
    for (int e = tid; e < 1024; e += 256) {
        float v = fdec(col_min_sm[e]) + y2_sm[e];           // + y2_j for col e
        atomicMin(&g_colmin[n * T + e], fenc(v));
    }
    if (tid < 64)
        atomicMin(&g_rowmin[n * T + i0 + tid], row_min_sm[tid]);  // already encoded

    // ---- fence-free completion protocol (16 blocks per batch) ----
    __builtin_amdgcn_s_waitcnt(0);   // this wave's atomics acked at coherent point
    __syncthreads();                 // all waves of block done
    if (tid == 0)
        last_sm = __hip_atomic_fetch_add(&batch_cnt[n], 1u, __ATOMIC_RELAXED,
                                         __HIP_MEMORY_SCOPE_AGENT);
    __syncthreads();
    if (last_sm != 15u) return;

    // last block of batch n: reduce its 1024 row/col mins (already full d^2)
    float sc = 0.f, sr = 0.f;
    for (int e = tid; e < T; e += 256) {
        unsigned cu = __hip_atomic_load(&g_colmin[n * T + e], __ATOMIC_RELAXED,
                                        __HIP_MEMORY_SCOPE_AGENT);
        unsigned ru = __hip_atomic_load(&g_rowmin[n * T + e], __ATOMIC_RELAXED,
                                        __HIP_MEMORY_SCOPE_AGENT);
        sc += sqrtf(fmaxf(fdec(cu), 0.f));
        sr += sqrtf(fmaxf(fdec(ru), 0.f));
    }
    #pragma unroll
    for (int o = 1; o < 64; o <<= 1) {
        sc += __shfl_xor(sc, o);
        sr += __shfl_xor(sr, o);
    }
    if (lane == 0) { red_sm[wave] = sc; red_sm[4 + wave] = sr; }
    __syncthreads();
    if (tid == 0) {
        atomicAdd(&sums[0], red_sm[0] + red_sm[1] + red_sm[2] + red_sm[3]);
        atomicAdd(&sums[1], red_sm[4] + red_sm[5] + red_sm[6] + red_sm[7]);
        __builtin_amdgcn_s_waitcnt(0);   // sums adds acked before counter bump
        unsigned old = __hip_atomic_fetch_add(g_cnt, 1u, __ATOMIC_RELAXED,
                                              __HIP_MEMORY_SCOPE_AGENT);
        if (old == NB - 1) {
            float a = __hip_atomic_load(&sums[0], __ATOMIC_RELAXED, __HIP_MEMORY_SCOPE_AGENT);
            float b = __hip_atomic_load(&sums[1], __ATOMIC_RELAXED, __HIP_MEMORY_SCOPE_AGENT);
            out[0] = fmaxf(a, b) * (1.0f / 67108864.0f);
        }
    }
}

extern "C" void kernel_launch(void* const* d_in, const int* in_sizes, int n_in,
                              void* d_out, int out_size, void* d_ws, size_t ws_size,
                              hipStream_t stream) {
    const float* x = (const float*)d_in[0];
    const float* y = (const float*)d_in[1];
    float* out = (float*)d_out;

    char* ws = (char*)d_ws;
    unsigned* g_colmin  = (unsigned*)(ws);                     // 256 KB
    unsigned* g_rowmin  = (unsigned*)(ws + 256 * 1024);        // 256 KB
    float*    y2g       = (float*)(ws + 512 * 1024);           // 256 KB
    float*    sums      = (float*)(ws + 768 * 1024);           // 2 f32
    unsigned* batch_cnt = (unsigned*)(ws + 768 * 1024 + 256);  // 64 u32
    unsigned* g_cnt     = (unsigned*)(ws + 768 * 1024 + 2048); // 1 u32
    short*    ybf       = (short*)(ws + 1024 * 1024);          // 16 MB

    wmd_prep<<<(NB * T * HD / 4) / 256, 256, 0, stream>>>(
        y, ybf, y2g, g_colmin, g_rowmin, sums, batch_cnt, g_cnt);
    wmd_main<<<dim3(16, NB), 256, 0, stream>>>(
        x, ybf, y2g, g_colmin, g_rowmin, sums, batch_cnt, g_cnt, out);
}

// Round 6
// 147.433 us; speedup vs baseline: 2.9631x; 1.0906x over previous
//
#include <hip/hip_runtime.h>

#define NB 64      // L*B batches
#define T 1024     // t1 == t2
#define HD 128     // h

// encoded +inf for order-preserving float-as-uint atomicMin
#define EINF 0xFF800000u

typedef __attribute__((ext_vector_type(8))) short bf16x8;
typedef __attribute__((ext_vector_type(4))) float f32x4;

static __device__ __forceinline__ short f2bf(float f) {
    unsigned u = __float_as_uint(f);
    u += 0x7FFFu + ((u >> 16) & 1u);
    return (short)(u >> 16);
}
static __device__ __forceinline__ unsigned fenc(float f) {
    unsigned b = __float_as_uint(f);
    return b ^ (unsigned)(((int)b >> 31) | (int)0x80000000);
}
static __device__ __forceinline__ float fdec(unsigned u) {
    unsigned m = (~(unsigned)((int)u >> 31)) | 0x80000000u;
    return __uint_as_float(u ^ m);
}

// Phase 0: y fp32 -> bf16 + y row norms + workspace init. ~51 MB, pure BW.
__global__ void wmd_prep(const float* __restrict__ y, short* __restrict__ ybf,
                         float* __restrict__ y2,
                         unsigned* __restrict__ g_colmin, unsigned* __restrict__ g_rowmin,
                         float* __restrict__ sums, unsigned* __restrict__ batch_cnt,
                         unsigned* __restrict__ g_cnt) {
    int gi = blockIdx.x * 256 + threadIdx.x;          // float4 index, 2.097M total
    float4 vy = reinterpret_cast<const float4*>(y)[gi];
    short4 sy;
    sy.x = f2bf(vy.x); sy.y = f2bf(vy.y); sy.z = f2bf(vy.z); sy.w = f2bf(vy.w);
    reinterpret_cast<short4*>(ybf)[gi] = sy;
    float py = vy.x * vy.x + vy.y * vy.y + vy.z * vy.z + vy.w * vy.w;
    py += __shfl_xor(py, 1);  py += __shfl_xor(py, 2);  py += __shfl_xor(py, 4);
    py += __shfl_xor(py, 8);  py += __shfl_xor(py, 16);
    if ((threadIdx.x & 31) == 0) y2[gi >> 5] = py;
    if (gi < NB * T) { g_colmin[gi] = EINF; g_rowmin[gi] = EINF; }
    if (gi < 2) sums[gi] = 0.f;
    if (gi >= 4 && gi < 4 + NB) batch_cnt[gi - 4] = 0u;
    if (gi == 4 + NB) g_cnt[0] = 0u;
}

// Phase 1: fused bf16-MFMA GEMM + min tracking + fence-free per-batch reduce.
// Round-6 synthesis of rounds 0-5 evidence:
//  - r0 (44 us): shared-LDS staging + per-phase barrier lockstep. Waves wait
//    ~90% of each phase (13.3k cy wall vs ~600 cy issue work); r2 proved DMA
//    depth doesn't fix it inside the lockstep.
//  - r5 (80 us): barrier-free is structurally sound (0 bank conflicts, no
//    spill) but global-B loads (~200-500 cy) + 1-deep window killed it.
// This round: WAVE-PRIVATE LDS double-buffers + ZERO main-loop barriers.
// Block = 64 rows x 512 cols, grid dim3(32, NB). Waves 2x2: wave (wr,wc) owns
// rows wr*32, cols wc*256, streams 16 private 16-col (4 KB) B tiles through
// its own 2-slot ring via global_load_lds (r0's exact XOR swizzle). Buffer
// reuse is guarded by the wave's OWN s_waitcnt vmcnt(4) — no __syncthreads in
// the loop, waves drift freely (latency hidden by 16 independent waves/CU).
// Per-word B LDS reads drop 4x vs r0 (1 wave per word, not 4). In-loop LDS
// atomics are gone: per-wave col-min slices go to private col_sm rows, merged
// once after one end barrier. No occupancy forcing (r1/r3/r4 lesson):
// __launch_bounds__(256) only; regs ~90, LDS ~39 KB -> 4 blocks/CU natural.
__global__ __launch_bounds__(256)
void wmd_main(const float* __restrict__ x, const short* __restrict__ ybf,
              const float* __restrict__ y2g,
              unsigned* __restrict__ g_colmin, unsigned* __restrict__ g_rowmin,
              float* __restrict__ sums, unsigned* __restrict__ batch_cnt,
              unsigned* __restrict__ g_cnt, float* __restrict__ out) {
    __shared__ short b_sm[4][2][2048];     // per-wave 2-slot x 4 KB ring (32 KB)
    __shared__ float y2_sm[512];
    __shared__ float x2_sm[64];
    __shared__ float col_sm[4][256];       // per-wave col-min slices (plain stores)
    __shared__ unsigned last_sm;
    __shared__ float red_sm[8];

    const int tid  = threadIdx.x;
    const int m    = blockIdx.x >> 1;      // i-tile 0..15 (64 rows)
    const int jh   = blockIdx.x & 1;       // j-half
    const int n    = blockIdx.y;           // batch
    const int i0   = m * 64;
    const int j0   = jh * 512;
    const int lane = tid & 63;
    const int wave = tid >> 6;
    const int wr   = wave >> 1;            // row stripe 0..1 (32 rows)
    const int wc   = wave & 1;             // col stripe 0..1 (256 cols)
    const int l16  = lane & 15, quad = lane >> 4;
    const float FINF = __uint_as_float(0x7F800000u);

// per wave: 4 x global_load_lds(16B) per 16-col tile into the wave's OWN slot.
// Linear LDS dest, XOR-swizzled global source (reader applies the same XOR).
#define ISSUE_GLLS(slot, tile)                                                    \
    {                                                                             \
        const short* ybase = ybf +                                                \
            (((size_t)(n * T + j0 + wc * 256 + (tile) * 16)) << 7);               \
        _Pragma("unroll")                                                         \
        for (int it = 0; it < 4; ++it) {                                          \
            int s   = it * 64 + lane;                                             \
            int row = s >> 4;                                                     \
            int c   = (s & 15) ^ (row & 7);                                       \
            const short* gp = ybase + row * 128 + c * 8;                          \
            __builtin_amdgcn_global_load_lds(                                     \
                (const __attribute__((address_space(1))) void*)gp,                \
                (__attribute__((address_space(3))) void*)&b_sm[wave][slot][it * 512], \
                16, 0, 0);                                                        \
        }                                                                         \
    }

    ISSUE_GLLS(0, 0);   // tile-0 DMA overlaps the prologue (drained by x use)

    // ---- A fragments: fp32 x -> bf16 regs + exact fp32 row norms ----
    // wc pair reads the same 32-row stripe (L1-shared); wc==0 publishes norms.
    bf16x8 af[2][4];
    #pragma unroll
    for (int mi = 0; mi < 2; ++mi) {
        float part = 0.f;
        #pragma unroll
        for (int kk = 0; kk < 4; ++kk) {
            const float4* gp = reinterpret_cast<const float4*>(
                x + (((size_t)(n * T + i0 + wr * 32 + mi * 16 + l16)) << 7) + kk * 32 + quad * 8);
            float4 a = gp[0], b = gp[1];
            bf16x8 f;
            f[0] = f2bf(a.x); f[1] = f2bf(a.y); f[2] = f2bf(a.z); f[3] = f2bf(a.w);
            f[4] = f2bf(b.x); f[5] = f2bf(b.y); f[6] = f2bf(b.z); f[7] = f2bf(b.w);
            af[mi][kk] = f;
            part += a.x * a.x + a.y * a.y + a.z * a.z + a.w * a.w;
            part += b.x * b.x + b.y * b.y + b.z * b.z + b.w * b.w;
        }
        part += __shfl_xor(part, 16);
        part += __shfl_xor(part, 32);
        if (wc == 0 && quad == 0) x2_sm[wr * 32 + mi * 16 + l16] = part;
    }
    #pragma unroll
    for (int e = tid; e < 512; e += 256) y2_sm[e] = y2g[n * T + j0 + e];

    float rmin[8];
    #pragma unroll
    for (int q = 0; q < 8; ++q) rmin[q] = FINF;

    __syncthreads();    // x2_sm/y2_sm visible (also drains own tile-0 DMA)

    float x2v[8];
    #pragma unroll
    for (int mi = 0; mi < 2; ++mi)
        #pragma unroll
        for (int r = 0; r < 4; ++r)
            x2v[mi * 4 + r] = x2_sm[wr * 32 + mi * 16 + quad * 4 + r];

    // ---- main loop: 16 private 16-col tiles; NO barriers ----
    #pragma unroll 2
    for (int t = 0; t < 16; ++t) {
        const int slot = t & 1;
        if (t < 15) ISSUE_GLLS(slot ^ 1, t + 1);
        // own-queue counted wait: tile t's 4 loads done; t+1's stay in flight.
        if (t < 15) asm volatile("s_waitcnt vmcnt(4)" ::: "memory");
        else        asm volatile("s_waitcnt vmcnt(0)" ::: "memory");

        float y2v = y2_sm[wc * 256 + t * 16 + l16];

        f32x4 acc[2];
        #pragma unroll
        for (int mi = 0; mi < 2; ++mi) {
            f32x4 z = {0.f, 0.f, 0.f, 0.f};
            acc[mi] = z;
        }

        #pragma unroll
        for (int kk = 0; kk < 4; ++kk) {
            int c = (kk * 4 + quad) ^ (l16 & 7);
            bf16x8 bv = *reinterpret_cast<const bf16x8*>(
                &b_sm[wave][slot][(l16 * 16 + c) * 8]);
            #pragma unroll
            for (int mi = 0; mi < 2; ++mi)
                acc[mi] = __builtin_amdgcn_mfma_f32_16x16x32_bf16(
                    af[mi][kk], bv, acc[mi], 0, 0, 0);
        }

        // ---- epilogue: fold mins (norm-add deferred) ----
        float vcol = FINF;
        #pragma unroll
        for (int mi = 0; mi < 2; ++mi)
            #pragma unroll
            for (int r = 0; r < 4; ++r) {
                float xy = acc[mi][r];
                rmin[mi * 4 + r] = fminf(rmin[mi * 4 + r], fmaf(-2.f, xy, y2v));
                vcol             = fminf(vcol,             fmaf(-2.f, xy, x2v[mi * 4 + r]));
            }
        vcol = fminf(vcol, __shfl_xor(vcol, 16));   // min over this wave's 32 rows
        vcol = fminf(vcol, __shfl_xor(vcol, 32));
        if (lane < 16)
            col_sm[wave][t * 16 + lane] = vcol;     // plain private store
    }

    // ---- rows: reduce over this wave's 256 cols, flush direct to global ----
    #pragma unroll
    for (int mi = 0; mi < 2; ++mi)
        #pragma unroll
        for (int r = 0; r < 4; ++r) {
            float v = rmin[mi * 4 + r] + x2v[mi * 4 + r];   // + x2_i
            v = fminf(v, __shfl_xor(v, 1));
            v = fminf(v, __shfl_xor(v, 2));
            v = fminf(v, __shfl_xor(v, 4));
            v = fminf(v, __shfl_xor(v, 8));
            if (l16 == 0)
                atomicMin(&g_rowmin[n * T + i0 + wr * 32 + mi * 16 + quad * 4 + r], fenc(v));
        }

    __syncthreads();   // col_sm slices complete across waves

    // ---- cols: merge the wr pair, add y2, flush to global ----
    #pragma unroll
    for (int e = tid; e < 512; e += 256) {
        int wcb = e >> 8, cc = e & 255;
        float v = fminf(col_sm[wcb][cc], col_sm[2 + wcb][cc]) + y2_sm[e];
        atomicMin(&g_colmin[n * T + j0 + e], fenc(v));
    }

    // ---- fence-free completion protocol (32 blocks per batch) ----
    __builtin_amdgcn_s_waitcnt(0);   // this wave's atomics acked at coherent point
    __syncthreads();                 // all waves of block done
    if (tid == 0)
        last_sm = __hip_atomic_fetch_add(&batch_cnt[n], 1u, __ATOMIC_RELAXED,
                                         __HIP_MEMORY_SCOPE_AGENT);
    __syncthreads();
    if (last_sm != 31u) return;

    // last block of batch n: reduce its 1024 row/col mins (already full d^2)
    float sc = 0.f, sr = 0.f;
    for (int e = tid; e < T; e += 256) {
        unsigned cu = __hip_atomic_load(&g_colmin[n * T + e], __ATOMIC_RELAXED,
                                        __HIP_MEMORY_SCOPE_AGENT);
        unsigned ru = __hip_atomic_load(&g_rowmin[n * T + e], __ATOMIC_RELAXED,
                                        __HIP_MEMORY_SCOPE_AGENT);
        sc += sqrtf(fmaxf(fdec(cu), 0.f));
        sr += sqrtf(fmaxf(fdec(ru), 0.f));
    }
    #pragma unroll
    for (int o = 1; o < 64; o <<= 1) {
        sc += __shfl_xor(sc, o);
        sr += __shfl_xor(sr, o);
    }
    if (lane == 0) { red_sm[wave] = sc; red_sm[4 + wave] = sr; }
    __syncthreads();
    if (tid == 0) {
        atomicAdd(&sums[0], red_sm[0] + red_sm[1] + red_sm[2] + red_sm[3]);
        atomicAdd(&sums[1], red_sm[4] + red_sm[5] + red_sm[6] + red_sm[7]);
        __builtin_amdgcn_s_waitcnt(0);   // sums adds acked before counter bump
        unsigned old = __hip_atomic_fetch_add(g_cnt, 1u, __ATOMIC_RELAXED,
                                              __HIP_MEMORY_SCOPE_AGENT);
        if (old == NB - 1) {
            float a = __hip_atomic_load(&sums[0], __ATOMIC_RELAXED, __HIP_MEMORY_SCOPE_AGENT);
            float b = __hip_atomic_load(&sums[1], __ATOMIC_RELAXED, __HIP_MEMORY_SCOPE_AGENT);
            out[0] = fmaxf(a, b) * (1.0f / 67108864.0f);
        }
    }
}

extern "C" void kernel_launch(void* const* d_in, const int* in_sizes, int n_in,
                              void* d_out, int out_size, void* d_ws, size_t ws_size,
                              hipStream_t stream) {
    const float* x = (const float*)d_in[0];
    const float* y = (const float*)d_in[1];
    float* out = (float*)d_out;

    char* ws = (char*)d_ws;
    unsigned* g_colmin  = (unsigned*)(ws);                     // 256 KB
    unsigned* g_rowmin  = (unsigned*)(ws + 256 * 1024);        // 256 KB
    float*    y2g       = (float*)(ws + 512 * 1024);           // 256 KB
    float*    sums      = (float*)(ws + 768 * 1024);           // 2 f32
    unsigned* batch_cnt = (unsigned*)(ws + 768 * 1024 + 256);  // 64 u32
    unsigned* g_cnt     = (unsigned*)(ws + 768 * 1024 + 2048); // 1 u32
    short*    ybf       = (short*)(ws + 1024 * 1024);          // 16 MB

    wmd_prep<<<(NB * T * HD / 4) / 256, 256, 0, stream>>>(
        y, ybf, y2g, g_colmin, g_rowmin, sums, batch_cnt, g_cnt);
    wmd_main<<<dim3(32, NB), 256, 0, stream>>>(
        x, ybf, y2g, g_colmin, g_rowmin, sums, batch_cnt, g_cnt, out);
}